// Round 5
// baseline (260.064 us; speedup 1.0000x reference)
//
#include <hip/hip_runtime.h>

#define TT 28
#define L2E 1.4426950408889634f

typedef __attribute__((ext_vector_type(8))) short bf16x8;
typedef __attribute__((ext_vector_type(4))) float f32x4;
typedef _Float16 h2 __attribute__((ext_vector_type(2)));
typedef __fp16 fp16x2 __attribute__((ext_vector_type(2)));

__device__ __forceinline__ unsigned fbits(float f){ union{float f; unsigned u;} v; v.f=f; return v.u; }
__device__ __forceinline__ float bitsf(unsigned u){ union{unsigned u; float f;} v; v.u=u; return v.f; }
__device__ __forceinline__ short bf16rnd(float f){ return (short)((fbits(f)+0x8000u)>>16); }

__device__ __forceinline__ h2 PKH2(float a, float b){
    fp16x2 t = __builtin_amdgcn_cvt_pkrtz(a, b);   // v_cvt_pkrtz_f16_f32
    return __builtin_bit_cast(h2, t);
}

#if __has_builtin(__builtin_amdgcn_fdot2)
#define FDOT2(a,b,c) __builtin_amdgcn_fdot2((a),(b),(c),false)
#else
__device__ __forceinline__ float FDOT2(h2 a, h2 b, float c){
    return fmaf((float)a.x,(float)b.x, fmaf((float)a.y,(float)b.y,(c)));
}
#endif
#if __has_builtin(__builtin_amdgcn_exp2f)
#define EXP2(x) __builtin_amdgcn_exp2f(x)
#else
#define EXP2(x) exp2f(x)
#endif
#if __has_builtin(__builtin_amdgcn_rcpf)
#define RCP(x) __builtin_amdgcn_rcpf(x)
#else
#define RCP(x) (1.f/(x))
#endif

// 32*4096 = 131072 rows. grid = 512 blocks * 4 waves = 2048 waves * 64 rows (1 lane = 1 row).
__global__ __launch_bounds__(256) __attribute__((amdgpu_waves_per_eu(2, 2)))
void horizon_kernel(
    const float* __restrict__ x, const float* __restrict__ last_step,
    const float* __restrict__ W_ih, const float* __restrict__ W_hh,
    const float* __restrict__ b_ih, const float* __restrict__ b_hh,
    const float* __restrict__ Wp, const float* __restrict__ bp,
    const float* __restrict__ Wo, const float* __restrict__ bo,
    const float* __restrict__ Wg1, const float* __restrict__ bg1,
    const float* __restrict__ Wg2, const float* __restrict__ bg2,
    const float* __restrict__ log_decay, float* __restrict__ out)
{
    // r/z rows pre-scaled by log2e, n rows by 2*log2e (folds exp->exp2 rescale into weights)
    __shared__ __attribute__((aligned(16))) float s_whh[24*8];
    __shared__ __attribute__((aligned(16))) float s_gate[28][12];  // [t][0..7]=Wg2*log2e, [8]=bg2*log2e
    __shared__ __attribute__((aligned(16))) float s_wiabc[32];     // (W_ih[o], b_ih[o]+b_hh[o])*log2e, o<16
    __shared__ __attribute__((aligned(16))) float s_wb4[32];       // j<8: (W_ih,b_ih,b_hh)[16+j]*2log2e, Wo[j]
    // per-wave scratch: Phase A park at [row*20+o] (<1280); t-loop stash at [row*36+t] (<2304)
    __shared__ __attribute__((aligned(16))) float s_dyn[4][64*36];

    const int tid = threadIdx.x;

    // ---- stage uniform weights into LDS (one barrier) ----
    if (tid < 192) s_whh[tid] = W_hh[tid] * (tid < 128 ? L2E : 2.0f*L2E);
    if (tid < 224) s_gate[tid>>3][tid&7] = Wg2[tid] * L2E;
    if (tid < 28)  s_gate[tid][8] = bg2[tid] * L2E;
    if (tid < 16){ s_wiabc[2*tid] = W_ih[tid]*L2E; s_wiabc[2*tid+1] = (b_ih[tid] + b_hh[tid])*L2E; }
    if (tid < 8){
        s_wb4[4*tid+0] = W_ih[16+tid]*2.0f*L2E;
        s_wb4[4*tid+1] = b_ih[16+tid]*2.0f*L2E;
        s_wb4[4*tid+2] = b_hh[16+tid]*2.0f*L2E;
        s_wb4[4*tid+3] = Wo[tid];
    }
    __syncthreads();   // only block-wide barrier; all later LDS use is per-wave

    const int lane = tid & 63;
    const int wv   = tid >> 6;
    const int c    = lane >> 4;   // k-chunk group
    const int rl   = lane & 15;   // A-row within 16 / B-output col
    const int group = blockIdx.x*4 + wv;
    float* dyn = &s_dyn[wv][0];

    // ---- Phase A: h0 = x@Wp^T + bp ; q = relu(x@Wg1^T + bg1), bf16 hi/lo MFMA ----
    const float* wrow = (rl < 8) ? (Wp + rl*256) : (Wg1 + (rl-8)*256);
    bf16x8 bfrag[8];
    #pragma unroll
    for (int kk=0; kk<8; ++kk){
        #pragma unroll
        for (int j=0; j<8; ++j) bfrag[kk][j] = bf16rnd(wrow[kk*32 + c*8 + j]);
    }
    const float aBias = (rl < 8) ? bp[rl] : bg1[rl-8];

    #pragma unroll 2
    for (int sub=0; sub<4; ++sub){
        const float* xrow = x + (size_t)(group*64 + sub*16 + rl) * 256;
        f32x4 acc = {0.f, 0.f, 0.f, 0.f};
        #pragma unroll
        for (int kk=0; kk<8; ++kk){
            float4 v0 = *(const float4*)(xrow + kk*32 + c*8);
            float4 v1 = *(const float4*)(xrow + kk*32 + c*8 + 4);
            float xs[8] = {v0.x,v0.y,v0.z,v0.w, v1.x,v1.y,v1.z,v1.w};
            bf16x8 ahi, alo;
            #pragma unroll
            for (int j=0; j<8; ++j){
                unsigned u  = fbits(xs[j]);
                unsigned hb = (u + 0x8000u) & 0xFFFF0000u;   // rounded bf16 "hi" as f32 bits
                ahi[j] = (short)(hb >> 16);
                alo[j] = bf16rnd(xs[j] - bitsf(hb));         // residual, rounded to bf16
            }
            acc = __builtin_amdgcn_mfma_f32_16x16x32_bf16(ahi, bfrag[kk], acc, 0, 0, 0);
            acc = __builtin_amdgcn_mfma_f32_16x16x32_bf16(alo, bfrag[kk], acc, 0, 0, 0);
        }
        // D layout: col = lane&15 (= output o), row = (lane>>4)*4 + r
        #pragma unroll
        for (int r=0; r<4; ++r){
            float v = acc[r] + aBias;
            if (rl >= 8) v = fmaxf(v, 0.f);
            dyn[(sub*16 + c*4 + r)*20 + rl] = v;
        }
    }
    // same-wave LDS ordering: no barrier needed

    // ---- gather per-row state (1 lane = 1 row) ----
    float h[8], q[8];
    #pragma unroll
    for (int j=0; j<8; ++j){ h[j] = dyn[lane*20 + j]; q[j] = dyn[lane*20 + 8 + j]; }

    // ---- all weights -> registers; W_hh as f16 pairs (96 VGPRs) for v_dot2 ----
    float w1[16], bb1[16];
    #pragma unroll
    for (int p=0; p<8; ++p){
        float4 wb = *(const float4*)&s_wiabc[p*4];
        w1[2*p] = wb.x; bb1[2*p] = wb.y; w1[2*p+1] = wb.z; bb1[2*p+1] = wb.w;
    }
    float w2[8], bi2[8], bh2c[8], wo8[8];
    #pragma unroll
    for (int j=0; j<8; ++j){
        float4 wb = *(const float4*)&s_wb4[4*j];
        w2[j] = wb.x; bi2[j] = wb.y; bh2c[j] = wb.z; wo8[j] = wb.w;
    }
    h2 whh2[24][4];
    #pragma unroll
    for (int o=0; o<24; ++o){
        float4 wa = *(const float4*)&s_whh[o*8];
        float4 wc = *(const float4*)&s_whh[o*8+4];
        whh2[o][0] = PKH2(wa.x, wa.y); whh2[o][1] = PKH2(wa.z, wa.w);
        whh2[o][2] = PKH2(wc.x, wc.y); whh2[o][3] = PKH2(wc.z, wc.w);
    }

    const int lrow  = group*64 + lane;
    const float ls0 = last_step[lrow];
    float cur   = ls0;
    const float df = __expf(-__expf(log_decay[0]));
    float decay = 1.f;
    const float boS = bo[0];

    #pragma unroll 1
    for (int t=0; t<TT; ++t){
        // LICM/sink fence: LDS may change -> pre-loop reg loads (whh2, w1, ...) cannot be
        // re-materialized as in-loop LDS reads; they must stay in registers.
        asm volatile("" ::: "memory");

        h2 hh[4];
        #pragma unroll
        for (int k=0; k<4; ++k) hh[k] = PKH2(h[2*k], h[2*k+1]);

        // r/z pre-activations (already *log2e): s[o] = cur*w1+bb1 + Whh[o].h
        float s[16];
        #pragma unroll
        for (int o=0; o<16; ++o){
            float a = fmaf(cur, w1[o], bb1[o]);
            #pragma unroll
            for (int k=0; k<4; ++k) a = FDOT2(hh[k], whh2[o][k], a);
            s[o] = a;
        }
        float nn[8], zz[8];
        #pragma unroll
        for (int o=0; o<8; ++o){
            float g = bh2c[o];                         // n-gate dot (already *2log2e)
            #pragma unroll
            for (int k=0; k<4; ++k) g = FDOT2(hh[k], whh2[16+o][k], g);
            float r  = RCP(1.f + EXP2(-s[o]));         // sigmoid (s pre-scaled)
            float un = fmaf(r, g, fmaf(cur, w2[o], bi2[o]));
            float e2 = EXP2(un);                       // e^(2*un_raw)
            nn[o] = fmaf(-2.f, RCP(e2 + 1.f), 1.f);    // tanh, saturates correctly
            zz[o] = RCP(1.f + EXP2(-s[8+o]));
        }
        float pred = boS;
        #pragma unroll
        for (int j=0; j<8; ++j){
            h[j] = fmaf(zz[j], h[j]-nn[j], nn[j]);     // (1-z)*n + z*h
            pred = fmaf(h[j], wo8[j], pred);
        }
        // gate_t = sigmoid(Wg2[t].q + bg2[t]) — in-loop LDS broadcast reads (required each step)
        float4 ga = *(const float4*)&s_gate[t][0];
        float4 gb = *(const float4*)&s_gate[t][4];
        float gl = s_gate[t][8];
        gl = fmaf(ga.x,q[0],gl); gl = fmaf(ga.y,q[1],gl); gl = fmaf(ga.z,q[2],gl); gl = fmaf(ga.w,q[3],gl);
        gl = fmaf(gb.x,q[4],gl); gl = fmaf(gb.y,q[5],gl); gl = fmaf(gb.z,q[6],gl); gl = fmaf(gb.w,q[7],gl);
        float gate = RCP(1.f + EXP2(-gl));

        decay *= df;
        float dp = ls0 * decay;                        // last_step * exp(-exp(ld)*(t+1))
        dyn[lane*36 + t] = fmaf(gate, pred - dp, dp);  // stride-36 stash (16B-aligned 4-groups)
        cur = pred;
    }

    // ---- final write, wave-contiguous: chunk i covers bytes [wavebase + i*1024, +1024) ----
    // float index f0 = i*256 + lane*4; 28%4==0 so each 4-group stays inside one row.
    float* wbase = out + (size_t)(group*64) * TT;
    #pragma unroll
    for (int i=0; i<7; ++i){
        int f0  = i*256 + lane*4;
        int row = f0 / 28;            // compiler magic-mul
        int tt  = f0 - row*28;        // multiple of 4
        float4 v = *(const float4*)&dyn[row*36 + tt];   // aligned: (36*row+tt)%4==0
        *(float4*)(wbase + f0) = v;
    }
}

extern "C" void kernel_launch(void* const* d_in, const int* in_sizes, int n_in,
                              void* d_out, int out_size, void* d_ws, size_t ws_size,
                              hipStream_t stream)
{
    const float* x         = (const float*)d_in[0];
    const float* last_step = (const float*)d_in[1];
    const float* W_ih      = (const float*)d_in[2];
    const float* W_hh      = (const float*)d_in[3];
    const float* b_ih      = (const float*)d_in[4];
    const float* b_hh      = (const float*)d_in[5];
    const float* Wp        = (const float*)d_in[6];
    const float* bp        = (const float*)d_in[7];
    const float* Wo        = (const float*)d_in[8];
    const float* bo        = (const float*)d_in[9];
    const float* Wg1       = (const float*)d_in[10];
    const float* bg1       = (const float*)d_in[11];
    const float* Wg2       = (const float*)d_in[12];
    const float* bg2       = (const float*)d_in[13];
    const float* log_decay = (const float*)d_in[14];

    hipLaunchKernelGGL(horizon_kernel, dim3(512), dim3(256), 0, stream,
                       x, last_step, W_ih, W_hh, b_ih, b_hh, Wp, bp, Wo, bo,
                       Wg1, bg1, Wg2, bg2, log_decay, (float*)d_out);
}

// Round 6
// 234.171 us; speedup vs baseline: 1.1106x; 1.1106x over previous
//
#include <hip/hip_runtime.h>

#define TT 28
#define L2E 1.4426950408889634f

typedef __attribute__((ext_vector_type(8))) short bf16x8;
typedef __attribute__((ext_vector_type(4))) float f32x4;
typedef _Float16 h2 __attribute__((ext_vector_type(2)));
typedef __fp16 fp16x2 __attribute__((ext_vector_type(2)));

__device__ __forceinline__ unsigned fbits(float f){ union{float f; unsigned u;} v; v.f=f; return v.u; }
__device__ __forceinline__ float bitsf(unsigned u){ union{unsigned u; float f;} v; v.u=u; return v.f; }
__device__ __forceinline__ short bf16rnd(float f){ return (short)((fbits(f)+0x8000u)>>16); }

__device__ __forceinline__ h2 PKH2(float a, float b){
    fp16x2 t = __builtin_amdgcn_cvt_pkrtz(a, b);   // v_cvt_pkrtz_f16_f32
    return __builtin_bit_cast(h2, t);
}

#if __has_builtin(__builtin_amdgcn_fdot2)
#define FDOT2(a,b,c) __builtin_amdgcn_fdot2((a),(b),(c),false)
#else
__device__ __forceinline__ float FDOT2(h2 a, h2 b, float c){
    return fmaf((float)a.x,(float)b.x, fmaf((float)a.y,(float)b.y,(c)));
}
#endif
#if __has_builtin(__builtin_amdgcn_exp2f)
#define EXP2(x) __builtin_amdgcn_exp2f(x)
#else
#define EXP2(x) exp2f(x)
#endif
#if __has_builtin(__builtin_amdgcn_rcpf)
#define RCP(x) __builtin_amdgcn_rcpf(x)
#else
#define RCP(x) (1.f/(x))
#endif

// quad_perm DPP: xor1 = [1,0,3,2] = 0xB1, xor2 = [2,3,0,1] = 0x4E. Full-rate VALU, no LDS pipe.
#if __has_builtin(__builtin_amdgcn_mov_dpp)
#define DPP_XOR1(x) __builtin_bit_cast(float, __builtin_amdgcn_mov_dpp(__builtin_bit_cast(int,(float)(x)), 0xB1, 0xF, 0xF, true))
#define DPP_XOR2(x) __builtin_bit_cast(float, __builtin_amdgcn_mov_dpp(__builtin_bit_cast(int,(float)(x)), 0x4E, 0xF, 0xF, true))
#else
#define DPP_XOR1(x) __shfl_xor((x), 1, 64)
#define DPP_XOR2(x) __shfl_xor((x), 2, 64)
#endif

// 131072 rows. 2048 blocks x 256 threads; Phase A: 4 waves x 16 rows (MFMA);
// Phase B: 4 lanes per row (lane owns h-dims o and o+4), 64 rows/block.
__global__ __launch_bounds__(256) __attribute__((amdgpu_waves_per_eu(5, 8)))
void horizon_kernel(
    const float* __restrict__ x, const float* __restrict__ last_step,
    const float* __restrict__ W_ih, const float* __restrict__ W_hh,
    const float* __restrict__ b_ih, const float* __restrict__ b_hh,
    const float* __restrict__ Wp, const float* __restrict__ bp,
    const float* __restrict__ Wo, const float* __restrict__ bo,
    const float* __restrict__ Wg1, const float* __restrict__ bg1,
    const float* __restrict__ Wg2, const float* __restrict__ bg2,
    const float* __restrict__ log_decay, float* __restrict__ out)
{
    // r/z rows pre-scaled by log2e, n rows by 2*log2e (folds exp->exp2 into weights)
    __shared__ __attribute__((aligned(16))) float s_whh[24*8];
    __shared__ __attribute__((aligned(16))) float s_wih[24];
    __shared__ __attribute__((aligned(16))) float s_b1[16];   // (b_ih+b_hh)[0..15]*L2E
    __shared__ __attribute__((aligned(16))) float s_bin[8];   // b_ih[16..]*2L2E
    __shared__ __attribute__((aligned(16))) float s_bhn[8];   // b_hh[16..]*2L2E
    __shared__ __attribute__((aligned(16))) float s_wo[8];
    __shared__ __attribute__((aligned(16))) float s_gw[28*8]; // Wg2*L2E
    __shared__ __attribute__((aligned(16))) float s_gb[28];   // bg2*L2E
    __shared__ __attribute__((aligned(16))) float s_park[64][17]; // [row][0..7]=h0, [8..15]=q

    const int tid = threadIdx.x;

    if (tid < 192) s_whh[tid] = W_hh[tid] * (tid < 128 ? L2E : 2.0f*L2E);
    if (tid < 224) s_gw[tid]  = Wg2[tid] * L2E;
    if (tid < 28)  s_gb[tid]  = bg2[tid] * L2E;
    if (tid < 24)  s_wih[tid] = W_ih[tid] * (tid < 16 ? L2E : 2.0f*L2E);
    if (tid < 16)  s_b1[tid]  = (b_ih[tid] + b_hh[tid]) * L2E;
    if (tid < 8){
        s_bin[tid] = b_ih[16+tid] * (2.0f*L2E);
        s_bhn[tid] = b_hh[16+tid] * (2.0f*L2E);
        s_wo[tid]  = Wo[tid];
    }
    __syncthreads();   // only barrier: staging -> everything below is per-wave/per-lane

    const int lane = tid & 63;
    const int wv   = tid >> 6;
    const int c    = lane >> 4;   // k-chunk group
    const int rl   = lane & 15;   // A-row within 16 / B-output col
    const int rowBase = blockIdx.x * 64;

    // ---- Phase A: wave wv computes rows rowBase+wv*16..+15, outputs h0(Wp)+q(Wg1) ----
    {
        const float* wrow = (rl < 8) ? (Wp + rl*256) : (Wg1 + (rl-8)*256);
        bf16x8 bfrag[8];
        #pragma unroll
        for (int kk=0; kk<8; ++kk){
            #pragma unroll
            for (int j=0; j<8; ++j) bfrag[kk][j] = bf16rnd(wrow[kk*32 + c*8 + j]);
        }
        const float aBias = (rl < 8) ? bp[rl] : bg1[rl-8];
        const float* xrow = x + (size_t)(rowBase + wv*16 + rl) * 256;
        f32x4 acc = {0.f, 0.f, 0.f, 0.f};
        #pragma unroll
        for (int kk=0; kk<8; ++kk){
            float4 v0 = *(const float4*)(xrow + kk*32 + c*8);
            float4 v1 = *(const float4*)(xrow + kk*32 + c*8 + 4);
            float xs[8] = {v0.x,v0.y,v0.z,v0.w, v1.x,v1.y,v1.z,v1.w};
            bf16x8 ahi, alo;
            #pragma unroll
            for (int j=0; j<8; ++j){
                unsigned u  = fbits(xs[j]);
                unsigned hb = (u + 0x8000u) & 0xFFFF0000u;   // rounded bf16 "hi"
                ahi[j] = (short)(hb >> 16);
                alo[j] = bf16rnd(xs[j] - bitsf(hb));         // residual -> bf16
            }
            acc = __builtin_amdgcn_mfma_f32_16x16x32_bf16(ahi, bfrag[kk], acc, 0, 0, 0);
            acc = __builtin_amdgcn_mfma_f32_16x16x32_bf16(alo, bfrag[kk], acc, 0, 0, 0);
        }
        // D layout: col = lane&15 (output o), row = c*4 + r
        #pragma unroll
        for (int r=0; r<4; ++r){
            float v = acc[r] + aBias;
            if (rl >= 8) v = fmaxf(v, 0.f);
            s_park[wv*16 + c*4 + r][rl] = v;
        }
    }
    // Phase B below reads only rows this same wave wrote -> per-wave LDS ordering suffices.

    // ---- Phase B: 4 lanes per row; lane owns dims o and o+4 ----
    const int row = tid >> 2;     // local row 0..63 (wave w handles rows 16w..16w+15)
    const int o   = tid & 3;
    const int rowG = rowBase + row;
    const int dd0 = o, dd1 = o^1, dd2 = o^2, dd3 = o^3;   // per-lane dim order after DPP allgather

    // h0 in dd-order + own f32 copies
    float harr[8];
    harr[0]=s_park[row][dd0]; harr[1]=s_park[row][dd1]; harr[2]=s_park[row][dd2]; harr[3]=s_park[row][dd3];
    harr[4]=s_park[row][4+dd0]; harr[5]=s_park[row][4+dd1]; harr[6]=s_park[row][4+dd2]; harr[7]=s_park[row][4+dd3];
    float hOwn0 = harr[0], hOwn1 = harr[4];
    h2 hh[4] = { PKH2(harr[0],harr[1]), PKH2(harr[2],harr[3]),
                 PKH2(harr[4],harr[5]), PKH2(harr[6],harr[7]) };

    // per-lane W_hh rows (6) packed in dd-order: r:{o,o+4} z:{8+o,12+o} n:{16+o,20+o}
    const int rws[6] = { o, o+4, 8+o, 12+o, 16+o, 20+o };
    h2 wk[6][4];
    #pragma unroll
    for (int rr=0; rr<6; ++rr){
        const float* wp_ = &s_whh[rws[rr]*8];
        wk[rr][0] = PKH2(wp_[dd0], wp_[dd1]); wk[rr][1] = PKH2(wp_[dd2], wp_[dd3]);
        wk[rr][2] = PKH2(wp_[4+dd0], wp_[4+dd1]); wk[rr][3] = PKH2(wp_[4+dd2], wp_[4+dd3]);
    }
    const float w_r0 = s_wih[o],    w_r1 = s_wih[o+4];
    const float w_z0 = s_wih[8+o],  w_z1 = s_wih[12+o];
    const float w_n0 = s_wih[16+o], w_n1 = s_wih[20+o];
    const float b_r0 = s_b1[o],   b_r1 = s_b1[o+4];
    const float b_z0 = s_b1[8+o], b_z1 = s_b1[12+o];
    const float b_in0 = s_bin[o], b_in1 = s_bin[o+4];
    const float b_hn0 = s_bhn[o], b_hn1 = s_bhn[o+4];
    h2 wo2[4] = { PKH2(s_wo[dd0], s_wo[dd1]), PKH2(s_wo[dd2], s_wo[dd3]),
                  PKH2(s_wo[4+dd0], s_wo[4+dd1]), PKH2(s_wo[4+dd2], s_wo[4+dd3]) };

    // gates fully pre-loop: lane o handles t = 4i+o
    float qv[8];
    #pragma unroll
    for (int j=0; j<8; ++j) qv[j] = s_park[row][8+j];
    float gates[7];
    #pragma unroll
    for (int i=0; i<7; ++i){
        const int t = 4*i + o;
        const float* gw = &s_gw[t*8];
        float gl = s_gb[t];
        #pragma unroll
        for (int j=0; j<8; ++j) gl = fmaf(gw[j], qv[j], gl);
        gates[i] = RCP(1.f + EXP2(-gl));
    }

    const float ls0 = last_step[rowG];
    const float boS = bo[0];
    float cur = ls0;
    float preds[7];

    #pragma unroll
    for (int t=0; t<TT; ++t){
        // 6 register-resident dot products (dot2, f16 weights/h)
        float sr0 = fmaf(cur, w_r0, b_r0), sr1 = fmaf(cur, w_r1, b_r1);
        float sz0 = fmaf(cur, w_z0, b_z0), sz1 = fmaf(cur, w_z1, b_z1);
        float gn0 = b_hn0, gn1 = b_hn1;
        #pragma unroll
        for (int k=0; k<4; ++k){
            sr0 = FDOT2(hh[k], wk[0][k], sr0);
            sr1 = FDOT2(hh[k], wk[1][k], sr1);
            sz0 = FDOT2(hh[k], wk[2][k], sz0);
            sz1 = FDOT2(hh[k], wk[3][k], sz1);
            gn0 = FDOT2(hh[k], wk[4][k], gn0);
            gn1 = FDOT2(hh[k], wk[5][k], gn1);
        }
        float r0 = RCP(1.f + EXP2(-sr0)), r1 = RCP(1.f + EXP2(-sr1));
        float e0 = EXP2(fmaf(r0, gn0, fmaf(cur, w_n0, b_in0)));
        float e1 = EXP2(fmaf(r1, gn1, fmaf(cur, w_n1, b_in1)));
        float nn0 = fmaf(-2.f, RCP(e0 + 1.f), 1.f);   // tanh, correct saturation
        float nn1 = fmaf(-2.f, RCP(e1 + 1.f), 1.f);
        float z0 = RCP(1.f + EXP2(-sz0)), z1 = RCP(1.f + EXP2(-sz1));
        hOwn0 = fmaf(z0, hOwn0 - nn0, nn0);
        hOwn1 = fmaf(z1, hOwn1 - nn1, nn1);

        // allgather h_new across the 4-lane group (quad_perm DPP, VALU-rate)
        float a0 = DPP_XOR1(hOwn0), a1 = DPP_XOR1(hOwn1);
        float u0 = DPP_XOR2(hOwn0), u1 = DPP_XOR2(a0);
        float u2 = DPP_XOR2(hOwn1), u3 = DPP_XOR2(a1);
        hh[0] = PKH2(hOwn0, a0); hh[1] = PKH2(u0, u1);
        hh[2] = PKH2(hOwn1, a1); hh[3] = PKH2(u2, u3);

        // pred = Wo.h_new + bo (local full dot; all 4 lanes agree)
        float p = boS;
        #pragma unroll
        for (int k=0; k<4; ++k) p = FDOT2(hh[k], wo2[k], p);
        preds[t>>2] = ((t & 3) == o) ? p : preds[t>>2];   // keep own t's
        cur = p;
    }

    // ---- combine with decay + store (lane writes its 7 t's) ----
    const float lam = EXP2(log_decay[0] * L2E);           // exp(log_decay)
    const float c1  = -lam * L2E;                          // exp(-lam*T) = EXP2(c1*T)
    float* orow = out + (size_t)rowG * TT;
    #pragma unroll
    for (int i=0; i<7; ++i){
        const int t = 4*i + o;
        float dp = ls0 * EXP2(c1 * (float)(t+1));
        orow[t] = fmaf(gates[i], preds[i] - dp, dp);
    }
}

extern "C" void kernel_launch(void* const* d_in, const int* in_sizes, int n_in,
                              void* d_out, int out_size, void* d_ws, size_t ws_size,
                              hipStream_t stream)
{
    const float* x         = (const float*)d_in[0];
    const float* last_step = (const float*)d_in[1];
    const float* W_ih      = (const float*)d_in[2];
    const float* W_hh      = (const float*)d_in[3];
    const float* b_ih      = (const float*)d_in[4];
    const float* b_hh      = (const float*)d_in[5];
    const float* Wp        = (const float*)d_in[6];
    const float* bp        = (const float*)d_in[7];
    const float* Wo        = (const float*)d_in[8];
    const float* bo        = (const float*)d_in[9];
    const float* Wg1       = (const float*)d_in[10];
    const float* bg1       = (const float*)d_in[11];
    const float* Wg2       = (const float*)d_in[12];
    const float* bg2       = (const float*)d_in[13];
    const float* log_decay = (const float*)d_in[14];

    hipLaunchKernelGGL(horizon_kernel, dim3(2048), dim3(256), 0, stream,
                       x, last_step, W_ih, W_hh, b_ih, b_hh, Wp, bp, Wo, bo,
                       Wg1, bg1, Wg2, bg2, log_decay, (float*)d_out);
}